// Round 9
// baseline (277.120 us; speedup 1.0000x reference)
//
#include <hip/hip_runtime.h>

typedef unsigned long long ull;

#define HH 256
#define WW 256
#define PLANE (HH*WW)
#define TILE 16              // inner tile (square)
#define TT 8
#define EXT 32               // ext rows/cols
#define NP 16                // uv-pairs per ext row
#define RS 68                // floats per LDS row (16 data pairs + 1 pad pair)
#define RPT 8                // rows per lane (4 row-groups x 16 col-pairs = 64 lanes)
#define LBUF (4 + EXT*RS)    // 2180 floats = 8720 B per buffer

#define RING_OFS (2u*1024u*1024u)   // float offset of ring slot 1 (8 MB)
#define FLAG_OFS (4u*1024u*1024u)   // float offset of flag array (16 MB)
#define RIMG (HH*(WW/2)*4)          // floats per interleaved ring image
#define NBLK 2048

__global__ __launch_bounds__(64, 2)
void hs_wave(const float* __restrict__ x,     // (8,3,256,256): It, Ix, Iy
             const float* __restrict__ est,   // (8,2,256,256): u0, v0
             float* __restrict__ out,         // (8,2,256,256)
             float* __restrict__ ws)          // rings (double-buffered) + flags
{
    __shared__ __align__(16) float s0[LBUF];
    __shared__ __align__(16) float s1[LBUF];

    const int img = blockIdx.x, cs = blockIdx.y, rb = blockIdx.z;
    const int tid = threadIdx.x;           // 0..63, one wave
    const int er0 = rb*TILE - TT;
    const int ec0 = cs*TILE - TT;
    const int blin = (img*16 + cs)*16 + rb;   // 0..2047
    unsigned* flags = (unsigned*)(ws + FLAG_OFS);

    // neighbor block id for the 8 poller lanes (same image, 8-neighborhood)
    int nb = -1;
    if (tid < 8) {
        int t = (tid < 4) ? tid : tid + 1;    // skip (0,0)
        int dr = t/3 - 1, dc = t%3 - 1;
        int nrb = rb + dr, ncs = cs + dc;
        if (nrb >= 0 && nrb < 16 && ncs >= 0 && ncs < 16)
            nb = (img*16 + ncs)*16 + nrb;
    }

    // ---- per-lane sweep geometry: 2 adjacent uv-cols x 8 rows ----
    const int cp = tid & 15;               // col-pair 0..15
    const int rg = tid >> 4;               // row-group 0..3
    const int r0 = rg * RPT;
    const int fb = 4 + 4*cp;               // float offset of col pair within row 0
    const int rm = (r0 == 0) ? 0 : r0 - 1;             // clamp: feeds d=0 ring only
    const int rN = (r0 + RPT > EXT-1) ? EXT-1 : r0+RPT;// clamp: feeds d=0 ring only

    // ---- per-pixel update coefficients, computed ONCE, live in registers ----
    float2 ca[RPT], cb[RPT], cc[RPT], cd[RPT], ce[RPT];
    {
        const float* __restrict__ xit = x + img*3*PLANE;
        const float* __restrict__ xix = xit + PLANE;
        const float* __restrict__ xiy = xix + PLANE;
        #pragma unroll
        for (int i = 0; i < RPT; ++i) {
            int gr = er0 + r0 + i;
            #pragma unroll
            for (int j = 0; j < 2; ++j) {
                int gc = ec0 + 2*cp + j;
                float A=0.f, B=0.f, C=0.f, D=0.f, E=0.f;
                if (gr >= 0 && gr < HH && gc >= 0 && gc < WW) {
                    int q = gr*WW + gc;
                    float it = xit[q], ix = xix[q], iy = xiy[q];
                    float rd = 1.0f / (1.0f + ix*ix + iy*iy);
                    const float s12 = 1.0f/12.0f;
                    A = (1.0f - ix*ix*rd) * s12;
                    B = (ix*iy*rd) * s12;
                    C = ix*it*rd;
                    D = (1.0f - iy*iy*rd) * s12;
                    E = iy*it*rd;
                }
                if (j == 0) { ca[i].x=A; cb[i].x=B; cc[i].x=C; cd[i].x=D; ce[i].x=E; }
                else        { ca[i].y=A; cb[i].y=B; cc[i].y=C; cd[i].y=D; ce[i].y=E; }
            }
        }
    }

    // ---- initial full ext-tile stage from est (interleave on the fly) ----
    {
        const float* __restrict__ eu = est + img*2*PLANE;
        const float* __restrict__ ev = eu + PLANE;
        #pragma unroll
        for (int q = 0; q < 8; ++q) {                 // 512 pairs, 8 per lane
            int k = tid + 64*q;
            int r = k >> 4, pc = k & 15;
            int gr = er0 + r, gc = ec0 + 2*pc;
            float2 uu = make_float2(0.f,0.f), vv = make_float2(0.f,0.f);
            if (gr >= 0 && gr < HH && gc >= 0 && gc < WW) {
                uu = *(const float2*)(eu + gr*WW + gc);
                vv = *(const float2*)(ev + gr*WW + gc);
            }
            *(float4*)(s0 + 4 + RS*r + 4*pc) = make_float4(uu.x, vv.x, uu.y, vv.y);
        }
    }
    __syncthreads();   // 1-wave block: lowers to waitcnt, no s_barrier

    // own-row center values, carried in registers
    float4 Mreg[RPT];
    #pragma unroll
    for (int j = 0; j < RPT; ++j)
        Mreg[j] = *(const float4*)(s0 + RS*(r0 + j) + fb);

    for (int p = 0; p < 13; ++p) {
        const int niter = (p < 12) ? TT : 4;

        // ---- niter iterations fully in LDS, ZERO barriers (wave-synchronous) ----
        for (int s = 1; s <= niter; ++s) {
            const float* __restrict__ rbuf = ((s-1)&1) ? s1 : s0;
            float* __restrict__ wbuf = (s&1) ? s1 : s0;
            const float* qb = rbuf + fb;

            // edge columns for rows rm, r0..r0+7, rN + boundary-row centers
            float2 L[RPT+2], R[RPT+2];
            const float* p0 = qb + RS*rm;
            const float* pN = qb + RS*rN;
            L[0] = *(const float2*)(p0 - 2);  R[0] = *(const float2*)(p0 + 4);
            #pragma unroll
            for (int j = 0; j < RPT; ++j) {
                const float* pr = qb + RS*(r0 + j);
                L[j+1] = *(const float2*)(pr - 2);
                R[j+1] = *(const float2*)(pr + 4);
            }
            L[RPT+1] = *(const float2*)(pN - 2);  R[RPT+1] = *(const float2*)(pN + 4);
            float4 Mb0 = *(const float4*)(p0);
            float4 MbN = *(const float4*)(pN);

            // horizontal [1,2,1] sums
            float2 hu[RPT+2], hv[RPT+2];
            hu[0] = make_float2(fmaf(2.f,Mb0.x,L[0].x)+Mb0.z, fmaf(2.f,Mb0.z,Mb0.x)+R[0].x);
            hv[0] = make_float2(fmaf(2.f,Mb0.y,L[0].y)+Mb0.w, fmaf(2.f,Mb0.w,Mb0.y)+R[0].y);
            #pragma unroll
            for (int j = 0; j < RPT; ++j) {
                float4 Mc = Mreg[j];
                hu[j+1] = make_float2(fmaf(2.f,Mc.x,L[j+1].x)+Mc.z, fmaf(2.f,Mc.z,Mc.x)+R[j+1].x);
                hv[j+1] = make_float2(fmaf(2.f,Mc.y,L[j+1].y)+Mc.w, fmaf(2.f,Mc.w,Mc.y)+R[j+1].y);
            }
            hu[RPT+1] = make_float2(fmaf(2.f,MbN.x,L[RPT+1].x)+MbN.z, fmaf(2.f,MbN.z,MbN.x)+R[RPT+1].x);
            hv[RPT+1] = make_float2(fmaf(2.f,MbN.y,L[RPT+1].y)+MbN.w, fmaf(2.f,MbN.w,MbN.y)+R[RPT+1].y);

            // vertical combine + coupled update + write + register carry
            #pragma unroll
            for (int j = 0; j < RPT; ++j) {
                float4 Mc = Mreg[j];
                float tux = fmaf(-4.f, Mc.x, fmaf(2.f, hu[j+1].x, hu[j].x) + hu[j+2].x);
                float tuy = fmaf(-4.f, Mc.z, fmaf(2.f, hu[j+1].y, hu[j].y) + hu[j+2].y);
                float tvx = fmaf(-4.f, Mc.y, fmaf(2.f, hv[j+1].x, hv[j].x) + hv[j+2].x);
                float tvy = fmaf(-4.f, Mc.w, fmaf(2.f, hv[j+1].y, hv[j].y) + hv[j+2].y);
                float2 un, vn;
                un.x = fmaf(ca[j].x, tux, -fmaf(cb[j].x, tvx, cc[j].x));
                un.y = fmaf(ca[j].y, tuy, -fmaf(cb[j].y, tvy, cc[j].y));
                vn.x = fmaf(cd[j].x, tvx, -fmaf(cb[j].x, tux, ce[j].x));
                vn.y = fmaf(cd[j].y, tvy, -fmaf(cb[j].y, tuy, ce[j].y));
                float4 nv = make_float4(un.x, vn.x, un.y, vn.y);
                *(float4*)(wbuf + RS*(r0 + j) + fb) = nv;
                Mreg[j] = nv;
            }
            // wave-synchronous LDS handoff: HW completion + compiler ordering fence
            asm volatile("s_waitcnt lgkmcnt(0)" ::: "memory");
        }
        // result now in s0 (niter even)

        if (p < 12) {
            float* ring = ws + (unsigned)(p & 1) * RING_OFS + img*RIMG;

            // ---- write inner 16x16 tile to ring (coherent 8B stores) ----
            #pragma unroll
            for (int q = 0; q < 2; ++q) {             // 128 pairs, 2 per lane
                int k = tid*2 + q;
                int r = k >> 3, pr = k & 7;
                const float* sp = s0 + 4 + RS*(r + TT) + 4*(pr + 4);
                float* gp = ring + ((rb*TILE + r)*(WW/2) + cs*8 + pr)*4;
                __hip_atomic_store((ull*)gp,     *(const ull*)sp,       __ATOMIC_RELAXED, __HIP_MEMORY_SCOPE_AGENT);
                __hip_atomic_store((ull*)gp + 1, *(const ull*)(sp + 2), __ATOMIC_RELAXED, __HIP_MEMORY_SCOPE_AGENT);
            }
            asm volatile("s_waitcnt vmcnt(0)" ::: "memory");   // drain ring stores
            if (tid == 0)
                __hip_atomic_store(&flags[p*NBLK + blin], 0x5eed0100u + (unsigned)p,
                                   __ATOMIC_RELAXED, __HIP_MEMORY_SCOPE_AGENT);
            asm volatile("" ::: "memory");
            if (tid < 8 && nb >= 0) {
                const unsigned tgt = 0x5eed0100u + (unsigned)p;
                while (__hip_atomic_load(&flags[p*NBLK + nb],
                                         __ATOMIC_RELAXED, __HIP_MEMORY_SCOPE_AGENT) != tgt)
                    __builtin_amdgcn_s_sleep(1);
            }
            __syncthreads();   // waitcnt + compiler fence (no s_barrier: 1 wave)

            // ---- restage ext halo ring from neighbors (coherent 8B loads) ----
            // rows 0..7 full (128 pairs) + rows 24..31 full (128) + rows 8..23 edges (128)
            #pragma unroll
            for (int q = 0; q < 6; ++q) {             // 384 pairs, 6 per lane
                int k = tid + 64*q;
                int r, pc;
                if (k < 128)      { r = k >> 4;            pc = k & 15; }
                else if (k < 256) { r = 24 + ((k-128) >> 4); pc = (k-128) & 15; }
                else { int m = k - 256; r = 8 + (m >> 3); int t = m & 7; pc = (t < 4) ? t : 8 + t; }
                int gr = er0 + r, gp2 = cs*8 - 4 + pc;
                ull v0 = 0, v1 = 0;
                if (gr >= 0 && gr < HH && gp2 >= 0 && gp2 < WW/2) {
                    const float* gp = ring + (gr*(WW/2) + gp2)*4;
                    v0 = __hip_atomic_load((const ull*)gp,     __ATOMIC_RELAXED, __HIP_MEMORY_SCOPE_AGENT);
                    v1 = __hip_atomic_load((const ull*)gp + 1, __ATOMIC_RELAXED, __HIP_MEMORY_SCOPE_AGENT);
                }
                float* sp = s0 + 4 + RS*r + 4*pc;
                *(ull*)sp = v0;
                *(ull*)(sp + 2) = v1;
            }
            __syncthreads();

            // refresh carried centers (restage rewrote halo rows/cols of s0)
            #pragma unroll
            for (int j = 0; j < RPT; ++j)
                Mreg[j] = *(const float4*)(s0 + RS*(r0 + j) + fb);
        }
    }

    // ---- final: de-interleave inner tile to planar out ----
    {
        float* ou = out + img*2*PLANE;
        float* ov = ou + PLANE;
        #pragma unroll
        for (int q = 0; q < 2; ++q) {                 // 128 pairs, 2 per lane
            int k = tid*2 + q;
            int r = k >> 3, pr = k & 7;
            float4 V = *(const float4*)(s0 + 4 + RS*(r + TT) + 4*(pr + 4));
            int gq = (rb*TILE + r)*WW + cs*TILE + 2*pr;
            *(float2*)(ou + gq) = make_float2(V.x, V.z);
            *(float2*)(ov + gq) = make_float2(V.y, V.w);
        }
    }
}

extern "C" void kernel_launch(void* const* d_in, const int* in_sizes, int n_in,
                              void* d_out, int out_size, void* d_ws, size_t ws_size,
                              hipStream_t stream) {
    const float* x   = (const float*)d_in[0];   // (8,3,256,256) fp32
    const float* est = (const float*)d_in[1];   // (8,2,256,256) fp32
    float* out = (float*)d_out;
    float* ws  = (float*)d_ws;                  // ring slot0 @0, slot1 @8MB, flags @16MB
                                                // flags 0xAA-poisoned each launch: != MAGIC, no reset needed

    // 2048 single-wave blocks; 17.4 KB LDS/block -> >=8 resident/CU,
    // capacity (>=8x256=2048) >= grid -> all co-resident, flag sync deadlock-free.
    dim3 grid(8, 16, 16);                       // (img, col-tile, row-tile)
    dim3 blk(64);
    hs_wave<<<grid, blk, 0, stream>>>(x, est, out, ws);
}

// Round 10
// 193.936 us; speedup vs baseline: 1.4289x; 1.4289x over previous
//
#include <hip/hip_runtime.h>

typedef unsigned long long ull;

#define HH 256
#define WW 256
#define PLANE (HH*WW)
#define TILE_R 32
#define TILE_C 64
#define TT 8
#define ER (TILE_R + 2*TT)   // 48 ext rows
#define EC (TILE_C + 2*TT)   // 80 ext cols (uv-pairs per row)
#define NCP (EC/2)           // 40 col-pairs per row
#define NRG 8                // row groups
#define RPT (ER/NRG)         // 6 rows per thread
#define NTHR 320             // = NCP*NRG, zero idle threads (5 waves)
#define LSZ (4 + ER*EC*2 + 4)   // floats: front pad + tile + end pad = 7688

#define RING_OFS (2u*1024u*1024u)   // float offset of ring slot 1 (8 MB)
#define FLAG_OFS (4u*1024u*1024u)   // float offset of flag array (16 MB)
#define RIMG (HH*(WW/2)*4)          // floats per interleaved ring image (131072)
#define NBLK 256

// one Jacobi step over this thread's 2 cols x 6 rows; own-row centers carried in Mreg
__device__ __forceinline__ void hs_step(
    const float* __restrict__ rbuf, float* __restrict__ wbuf,
    int fb, int rm, int r0, int rN,
    float4* __restrict__ Mreg,
    const float2* __restrict__ ca, const float2* __restrict__ cb,
    const float2* __restrict__ cc, const float2* __restrict__ cd,
    const float2* __restrict__ ce)
{
    const float* qb = rbuf + fb;

    // edge columns for rows rm, r0..r0+RPT-1, rN + boundary-row centers (LDS)
    float2 L[RPT+2], R[RPT+2];
    const float* p0 = qb + 160*rm;
    const float* pN = qb + 160*rN;
    L[0] = *(const float2*)(p0 - 2);  R[0] = *(const float2*)(p0 + 4);
    #pragma unroll
    for (int j = 0; j < RPT; ++j) {
        const float* pr = qb + 160*(r0 + j);
        L[j+1] = *(const float2*)(pr - 2);
        R[j+1] = *(const float2*)(pr + 4);
    }
    L[RPT+1] = *(const float2*)(pN - 2);  R[RPT+1] = *(const float2*)(pN + 4);
    float4 Mb0 = *(const float4*)(p0);
    float4 MbN = *(const float4*)(pN);

    // horizontal [1,2,1] sums
    float2 hu[RPT+2], hv[RPT+2];
    hu[0] = make_float2(fmaf(2.f,Mb0.x,L[0].x)+Mb0.z, fmaf(2.f,Mb0.z,Mb0.x)+R[0].x);
    hv[0] = make_float2(fmaf(2.f,Mb0.y,L[0].y)+Mb0.w, fmaf(2.f,Mb0.w,Mb0.y)+R[0].y);
    #pragma unroll
    for (int j = 0; j < RPT; ++j) {
        float4 Mc = Mreg[j];
        hu[j+1] = make_float2(fmaf(2.f,Mc.x,L[j+1].x)+Mc.z, fmaf(2.f,Mc.z,Mc.x)+R[j+1].x);
        hv[j+1] = make_float2(fmaf(2.f,Mc.y,L[j+1].y)+Mc.w, fmaf(2.f,Mc.w,Mc.y)+R[j+1].y);
    }
    hu[RPT+1] = make_float2(fmaf(2.f,MbN.x,L[RPT+1].x)+MbN.z, fmaf(2.f,MbN.z,MbN.x)+R[RPT+1].x);
    hv[RPT+1] = make_float2(fmaf(2.f,MbN.y,L[RPT+1].y)+MbN.w, fmaf(2.f,MbN.w,MbN.y)+R[RPT+1].y);

    // vertical combine + coupled update + write + register carry
    #pragma unroll
    for (int j = 0; j < RPT; ++j) {
        float4 Mc = Mreg[j];
        float tux = fmaf(-4.f, Mc.x, fmaf(2.f, hu[j+1].x, hu[j].x) + hu[j+2].x);
        float tuy = fmaf(-4.f, Mc.z, fmaf(2.f, hu[j+1].y, hu[j].y) + hu[j+2].y);
        float tvx = fmaf(-4.f, Mc.y, fmaf(2.f, hv[j+1].x, hv[j].x) + hv[j+2].x);
        float tvy = fmaf(-4.f, Mc.w, fmaf(2.f, hv[j+1].y, hv[j].y) + hv[j+2].y);
        float2 un, vn;
        un.x = fmaf(ca[j].x, tux, -fmaf(cb[j].x, tvx, cc[j].x));
        un.y = fmaf(ca[j].y, tuy, -fmaf(cb[j].y, tvy, cc[j].y));
        vn.x = fmaf(cd[j].x, tvx, -fmaf(cb[j].x, tux, ce[j].x));
        vn.y = fmaf(cd[j].y, tvy, -fmaf(cb[j].y, tuy, ce[j].y));
        float4 nv = make_float4(un.x, vn.x, un.y, vn.y);
        *(float4*)(wbuf + 160*(r0 + j) + fb) = nv;
        Mreg[j] = nv;
    }
}

__global__ __launch_bounds__(NTHR, 2)
void hs_mega(const float* __restrict__ x,     // (8,3,256,256): It, Ix, Iy
             const float* __restrict__ est,   // (8,2,256,256): u0, v0
             float* __restrict__ out,         // (8,2,256,256)
             float* __restrict__ ws)          // rings (double-buffered) + flags
{
    __shared__ __align__(16) float s0[LSZ];
    __shared__ __align__(16) float s1[LSZ];

    const int img = blockIdx.x, cs = blockIdx.y, rb = blockIdx.z;
    const int tid = threadIdx.x;
    const int er0 = rb*TILE_R - TT;
    const int ec0 = cs*TILE_C - TT;
    const int blin = (img*4 + cs)*8 + rb;      // 0..255
    unsigned* flags = (unsigned*)(ws + FLAG_OFS);

    // neighbor block id for the 8 poller threads (same image, 8-neighborhood)
    int nb = -1;
    if (tid < 8) {
        int t = (tid < 4) ? tid : tid + 1;     // skip (0,0)
        int dr = t/3 - 1, dc = t%3 - 1;
        int nrb = rb + dr, ncs = cs + dc;
        if (nrb >= 0 && nrb < 8 && ncs >= 0 && ncs < 4)
            nb = (img*4 + ncs)*8 + nrb;
    }

    // ---- per-thread sweep geometry: 2 adjacent uv-cols x RPT rows ----
    const int cp = tid % NCP;          // 0..39
    const int rg = tid / NCP;          // 0..7
    const int r0 = rg * RPT;
    const int fb = 4 + 4*cp;           // float index of col pair in row 0
    const int rm = (r0 == 0) ? 0 : r0 - 1;             // clamp: feeds d=0 ring only
    const int rN = (r0 + RPT > ER-1) ? ER-1 : r0+RPT;  // clamp: feeds d=0 ring only

    // ---- per-pixel update coefficients, computed ONCE, live in registers ----
    float2 ca[RPT], cb[RPT], cc[RPT], cd[RPT], ce[RPT];
    {
        const float* __restrict__ xit = x + img*3*PLANE;
        const float* __restrict__ xix = xit + PLANE;
        const float* __restrict__ xiy = xix + PLANE;
        #pragma unroll
        for (int i = 0; i < RPT; ++i) {
            int gr = er0 + r0 + i;
            #pragma unroll
            for (int j = 0; j < 2; ++j) {
                int gc = ec0 + 2*cp + j;
                float A=0.f, B=0.f, C=0.f, D=0.f, E=0.f;
                if (gr >= 0 && gr < HH && gc >= 0 && gc < WW) {
                    int q = gr*WW + gc;
                    float it = xit[q], ix = xix[q], iy = xiy[q];
                    float rd = 1.0f / (1.0f + ix*ix + iy*iy);
                    const float s12 = 1.0f/12.0f;
                    A = (1.0f - ix*ix*rd) * s12;
                    B = (ix*iy*rd) * s12;
                    C = ix*it*rd;
                    D = (1.0f - iy*iy*rd) * s12;
                    E = iy*it*rd;
                }
                if (j == 0) { ca[i].x=A; cb[i].x=B; cc[i].x=C; cd[i].x=D; ce[i].x=E; }
                else        { ca[i].y=A; cb[i].y=B; cc[i].y=C; cd[i].y=D; ce[i].y=E; }
            }
        }
    }

    // ---- initial full ext-tile stage from est (interleave on the fly) ----
    {
        const float* __restrict__ eu = est + img*2*PLANE;
        const float* __restrict__ ev = eu + PLANE;
        for (int k = tid; k < ER*NCP; k += NTHR) {           // 1920 chunks
            int r = k / NCP, c = k - r*NCP;
            int gr = er0 + r, gc = ec0 + 2*c;
            float2 uu = make_float2(0.f,0.f), vv = make_float2(0.f,0.f);
            if (gr >= 0 && gr < HH && gc >= 0 && gc < WW) {  // gc even -> pair in-bounds
                uu = *(const float2*)(eu + gr*WW + gc);
                vv = *(const float2*)(ev + gr*WW + gc);
            }
            *(float4*)(s0 + 4 + 160*r + 4*c) = make_float4(uu.x, vv.x, uu.y, vv.y);
        }
    }
    __syncthreads();

    // own-row center values, carried in registers; refreshed after each restage
    float4 Mreg[RPT];
    #pragma unroll
    for (int j = 0; j < RPT; ++j)
        Mreg[j] = *(const float4*)(s0 + 160*(r0 + j) + fb);

    for (int p = 0; p < 13; ++p) {
        // ---- steps fully unrolled, compile-time buffer parity, 1 barrier each ----
        if (p < 12) {
            #pragma unroll
            for (int q = 0; q < 4; ++q) {
                hs_step(s0, s1, fb, rm, r0, rN, Mreg, ca, cb, cc, cd, ce);
                __syncthreads();
                hs_step(s1, s0, fb, rm, r0, rN, Mreg, ca, cb, cc, cd, ce);
                __syncthreads();
            }
        } else {
            #pragma unroll
            for (int q = 0; q < 2; ++q) {
                hs_step(s0, s1, fb, rm, r0, rN, Mreg, ca, cb, cc, cd, ce);
                __syncthreads();
                hs_step(s1, s0, fb, rm, r0, rN, Mreg, ca, cb, cc, cd, ce);
                __syncthreads();
            }
        }
        // result now in s0

        if (p < 12) {
            float* ring = ws + (unsigned)(p & 1) * RING_OFS + img*RIMG;

            // ---- write depth-8 ring of inner tile (coherent 8B stores) ----
            for (int k = tid; k < 640; k += NTHR) {
                int m = k; int r, c2;
                if (m < 256)      { r = m >> 5;              c2 = m & 31; }
                else if (m < 512) { r = 24 + ((m-256) >> 5); c2 = (m-256) & 31; }
                else { int mm = m - 512; r = 8 + (mm >> 3); int t = mm & 7; c2 = (t < 4) ? t : 24 + t; }
                const float* sp = s0 + 4 + 160*(r + TT) + 4*(c2 + 4);  // ext col pair = c2+4
                float* gp = ring + ((rb*TILE_R + r)*(WW/2) + cs*(TILE_C/2) + c2)*4;
                __hip_atomic_store((ull*)gp,     *(const ull*)sp,       __ATOMIC_RELAXED, __HIP_MEMORY_SCOPE_AGENT);
                __hip_atomic_store((ull*)gp + 1, *(const ull*)(sp + 2), __ATOMIC_RELAXED, __HIP_MEMORY_SCOPE_AGENT);
            }
            asm volatile("s_waitcnt vmcnt(0)" ::: "memory");   // per-wave drain of ring stores
            __syncthreads();
            if (tid == 0)
                __hip_atomic_store(&flags[p*NBLK + blin], 0x5eed0100u + (unsigned)p,
                                   __ATOMIC_RELAXED, __HIP_MEMORY_SCOPE_AGENT);
            asm volatile("" ::: "memory");
            if (tid < 8 && nb >= 0) {
                const unsigned tgt = 0x5eed0100u + (unsigned)p;
                while (__hip_atomic_load(&flags[p*NBLK + nb],
                                         __ATOMIC_RELAXED, __HIP_MEMORY_SCOPE_AGENT) != tgt)
                    __builtin_amdgcn_s_sleep(1);
            }
            __syncthreads();

            // ---- restage ext halo ring from neighbors (coherent 8B loads) ----
            for (int k = tid; k < 896; k += NTHR) {
                int m = k; int r, c2;
                if (m < 320)      { r = m / 40;              c2 = m - (m/40)*40; }
                else if (m < 640) { int mm = m-320; r = 40 + mm/40; c2 = mm - (mm/40)*40; }
                else { int mm = m - 640; r = 8 + (mm >> 3); int t = mm & 7; c2 = (t < 4) ? t : 32 + t; }
                int gr = er0 + r, gc2 = cs*(TILE_C/2) - 4 + c2;
                ull v0 = 0, v1 = 0;
                if (gr >= 0 && gr < HH && gc2 >= 0 && gc2 < WW/2) {
                    const float* gp = ring + (gr*(WW/2) + gc2)*4;
                    v0 = __hip_atomic_load((const ull*)gp,     __ATOMIC_RELAXED, __HIP_MEMORY_SCOPE_AGENT);
                    v1 = __hip_atomic_load((const ull*)gp + 1, __ATOMIC_RELAXED, __HIP_MEMORY_SCOPE_AGENT);
                }
                float* sp = s0 + 4 + 160*r + 4*c2;
                *(ull*)sp = v0;
                *(ull*)(sp + 2) = v1;
            }
            __syncthreads();

            // refresh carried centers (restage rewrote halo regions of s0)
            #pragma unroll
            for (int j = 0; j < RPT; ++j)
                Mreg[j] = *(const float4*)(s0 + 160*(r0 + j) + fb);
        }
    }

    // ---- final: de-interleave inner tile to planar out ----
    {
        float* ou = out + img*2*PLANE;
        float* ov = ou + PLANE;
        for (int k = tid; k < 1024; k += NTHR) {
            int r = k >> 5, c2 = k & 31;
            float4 V = *(const float4*)(s0 + 4 + 160*(r + TT) + 4*(c2 + 4));
            int q = (rb*TILE_R + r)*WW + cs*TILE_C + 2*c2;
            *(float2*)(ou + q) = make_float2(V.x, V.z);
            *(float2*)(ov + q) = make_float2(V.y, V.w);
        }
    }
}

extern "C" void kernel_launch(void* const* d_in, const int* in_sizes, int n_in,
                              void* d_out, int out_size, void* d_ws, size_t ws_size,
                              hipStream_t stream) {
    const float* x   = (const float*)d_in[0];   // (8,3,256,256) fp32
    const float* est = (const float*)d_in[1];   // (8,2,256,256) fp32
    float* out = (float*)d_out;
    float* ws  = (float*)d_ws;                  // ring slot0 @0, slot1 @8MB, flags @16MB
                                                // flags 0xAA-poisoned each launch: != MAGIC, no reset needed

    dim3 grid(8, WW/TILE_C, HH/TILE_R);         // 256 blocks, all co-resident (1/CU by LDS)
    dim3 blk(NTHR);
    hs_mega<<<grid, blk, 0, stream>>>(x, est, out, ws);
}